// Round 2
// baseline (1522.291 us; speedup 1.0000x reference)
//
#include <hip/hip_runtime.h>
#include <hip/hip_bf16.h>

#define NN 50000   // nodes
#define NE 800000  // edges
#define NG 256     // graphs
#define CIN 128
#define CH 256

// ---------------- CSR build ----------------
__global__ void k_zero_ints(int* p, int n) {
    int i = blockIdx.x * 256 + threadIdx.x;
    if (i < n) p[i] = 0;
}

__global__ void k_count_deg(const int* __restrict__ dst, int* __restrict__ deg) {
    int e = blockIdx.x * 256 + threadIdx.x;
    if (e < NE) atomicAdd(&deg[dst[e]], 1);
}

// chunk=1024 per block (256 thr x 4)
__global__ void k_scan1(const int* __restrict__ deg, int* __restrict__ bsum) {
    __shared__ int sd[256];
    int base = blockIdx.x * 1024, t = threadIdx.x, s = 0;
    for (int j = 0; j < 4; j++) { int i = base + t * 4 + j; if (i < NN) s += deg[i]; }
    sd[t] = s; __syncthreads();
    for (int off = 128; off > 0; off >>= 1) { if (t < off) sd[t] += sd[t + off]; __syncthreads(); }
    if (t == 0) bsum[blockIdx.x] = sd[0];
}

__global__ void k_scan2(int* bsum, int nb, int* row_ptr) {
    if (threadIdx.x == 0 && blockIdx.x == 0) {
        int acc = 0;
        for (int i = 0; i < nb; i++) { int v = bsum[i]; bsum[i] = acc; acc += v; }
        row_ptr[NN] = NE;  // total degree == E
    }
}

__global__ void k_scan3(const int* __restrict__ deg, const int* __restrict__ bsum,
                        int* __restrict__ row_ptr) {
    __shared__ int sd[256];
    int base = blockIdx.x * 1024, t = threadIdx.x;
    int v[4]; int s = 0;
    for (int j = 0; j < 4; j++) { int i = base + t * 4 + j; v[j] = (i < NN) ? deg[i] : 0; s += v[j]; }
    sd[t] = s; __syncthreads();
    for (int off = 1; off < 256; off <<= 1) {        // Hillis-Steele inclusive
        int tmp = (t >= off) ? sd[t - off] : 0; __syncthreads();
        sd[t] += tmp; __syncthreads();
    }
    int run = bsum[blockIdx.x] + sd[t] - s;          // exclusive prefix for this thread
    for (int j = 0; j < 4; j++) { int i = base + t * 4 + j; if (i < NN) row_ptr[i] = run; run += v[j]; }
}

__global__ void k_fill(const int* __restrict__ src, const int* __restrict__ dst,
                       const int* __restrict__ row_ptr, int* __restrict__ fill,
                       int* __restrict__ col) {
    int e = blockIdx.x * 256 + threadIdx.x;
    if (e < NE) {
        int d = dst[e];
        int pos = row_ptr[d] + atomicAdd(&fill[d], 1);
        col[pos] = src[e];
    }
}

// ---------------- aggregation: z = h + sum_{j->i} h[j] ----------------
// layer 0: fp32 input, 128 ch, lane handles 2 channels
__global__ void k_agg0(const float* __restrict__ x, const int* __restrict__ row_ptr,
                       const int* __restrict__ col, float* __restrict__ z) {
    int gid = blockIdx.x * 256 + threadIdx.x;
    int node = gid >> 6, lane = threadIdx.x & 63;
    if (node >= NN) return;
    int c0 = lane * 2;
    float2 acc = *(const float2*)(x + (size_t)node * CIN + c0);
    int beg = row_ptr[node], end = row_ptr[node + 1];
    for (int e = beg; e < end; e++) {
        int s = col[e];
        float2 nv = *(const float2*)(x + (size_t)s * CIN + c0);
        acc.x += nv.x; acc.y += nv.y;
    }
    *(float2*)(z + (size_t)node * CIN + c0) = acc;
}

// layers 1..3: 256 ch, lane handles 4 channels
__global__ void k_agg(const float* __restrict__ h, const int* __restrict__ row_ptr,
                      const int* __restrict__ col, float* __restrict__ z) {
    int gid = blockIdx.x * 256 + threadIdx.x;
    int node = gid >> 6, lane = threadIdx.x & 63;
    if (node >= NN) return;
    int c0 = lane * 4;
    float4 acc = *(const float4*)(h + (size_t)node * CH + c0);
    int beg = row_ptr[node], end = row_ptr[node + 1];
    for (int e = beg; e < end; e++) {
        int s = col[e];
        float4 nv = *(const float4*)(h + (size_t)s * CH + c0);
        acc.x += nv.x; acc.y += nv.y; acc.z += nv.z; acc.w += nv.w;
    }
    *(float4*)(z + (size_t)node * CH + c0) = acc;
}

// ---------------- fused GEMM + bias + relu ----------------
// out[i, :] = relu(A[i, :K] @ W[K x 256] + b)    all fp32
// tile: 32 rows x 256 cols per block (full width => in-place safe:
// block reads A only from its own 32-row tile, writes same tile after reads)
template <int K>
__global__ __launch_bounds__(256) void k_gemm(const float* __restrict__ A,
                                              const float* __restrict__ W,
                                              const float* __restrict__ bias,
                                              float* __restrict__ out) {
    __shared__ float As[32][33];   // transposed A tile, padded
    __shared__ float Ws[32][256];  // W tile
    int tid = threadIdx.x;
    int i0 = blockIdx.x * 32;
    int c0 = (tid & 63) * 4;       // 4 cols per thread
    int r0 = (tid >> 6) * 8;       // 8 rows per thread
    float acc[8][4] = {};
    int lr = tid >> 3;             // load: row 0..31
    int lk = (tid & 7) * 4;        // load: k 0,4,..28
    int lrow = i0 + lr; if (lrow >= NN) lrow = NN - 1;

    for (int kb = 0; kb < K; kb += 32) {
        float4 av = *(const float4*)(A + (size_t)lrow * K + kb + lk);
        As[lk + 0][lr] = av.x; As[lk + 1][lr] = av.y;
        As[lk + 2][lr] = av.z; As[lk + 3][lr] = av.w;
        const float4* wp = (const float4*)(W + (size_t)kb * CH);
        float4* wsp = (float4*)&Ws[0][0];
#pragma unroll
        for (int j = 0; j < 8; j++) wsp[tid + j * 256] = wp[tid + j * 256];
        __syncthreads();
#pragma unroll
        for (int k = 0; k < 32; k++) {
            float4 wv = *(const float4*)&Ws[k][c0];
            float avr[8];
#pragma unroll
            for (int r = 0; r < 8; r++) avr[r] = As[k][r0 + r];  // wave-uniform broadcast
#pragma unroll
            for (int r = 0; r < 8; r++) {
                acc[r][0] += avr[r] * wv.x;
                acc[r][1] += avr[r] * wv.y;
                acc[r][2] += avr[r] * wv.z;
                acc[r][3] += avr[r] * wv.w;
            }
        }
        __syncthreads();
    }
    float4 bv = *(const float4*)(bias + c0);
#pragma unroll
    for (int r = 0; r < 8; r++) {
        int row = i0 + r0 + r;
        if (row < NN) {
            float4 o;
            o.x = fmaxf(acc[r][0] + bv.x, 0.f);
            o.y = fmaxf(acc[r][1] + bv.y, 0.f);
            o.z = fmaxf(acc[r][2] + bv.z, 0.f);
            o.w = fmaxf(acc[r][3] + bv.w, 0.f);
            *(float4*)(out + (size_t)row * CH + c0) = o;
        }
    }
}

// ---------------- global_add_pool ----------------
__global__ void k_ranges_init(int* gs, int* ge) {
    int g = threadIdx.x;
    gs[g] = NN; ge[g] = 0;
}
__global__ void k_ranges(const int* __restrict__ batch, int* gs, int* ge) {
    int i = blockIdx.x * 256 + threadIdx.x;
    if (i < NN) { int b = batch[i]; atomicMin(&gs[b], i); atomicMax(&ge[b], i + 1); }
}
__global__ void k_pool(const float* __restrict__ h, const int* __restrict__ gs,
                       const int* __restrict__ ge, float* __restrict__ out) {
    int g = blockIdx.x, c = threadIdx.x;
    int s = gs[g], e = ge[g];
    float acc = 0.f;
    for (int i = s; i < e; i++) acc += h[(size_t)i * CH + c];
    out[g * CH + c] = acc;
}

extern "C" void kernel_launch(void* const* d_in, const int* in_sizes, int n_in,
                              void* d_out, int out_size, void* d_ws, size_t ws_size,
                              hipStream_t stream) {
    const float* x     = (const float*)d_in[0];
    const int*   ei    = (const int*)d_in[1];
    const int*   batch = (const int*)d_in[2];
    const float* w1_0  = (const float*)d_in[3];
    const float* b1_0  = (const float*)d_in[4];
    const float* w2_0  = (const float*)d_in[5];
    const float* b2_0  = (const float*)d_in[6];
    const float* w1s   = (const float*)d_in[7];
    const float* b1s   = (const float*)d_in[8];
    const float* w2s   = (const float*)d_in[9];
    const float* b2s   = (const float*)d_in[10];
    float* out = (float*)d_out;

    char* p = (char*)d_ws;
    float* Hb = (float*)p; p += (size_t)NN * CH * 4;
    float* Tb = (float*)p; p += (size_t)NN * CH * 4;
    int* row_ptr = (int*)p; p += (size_t)(NN + 1) * 4;
    int* deg  = (int*)p; p += (size_t)NN * 4;
    int* fill = (int*)p; p += (size_t)NN * 4;      // must stay adjacent to deg (zeroed together)
    int* col  = (int*)p; p += (size_t)NE * 4;
    int* bsum = (int*)p; p += 64 * 4;
    int* gs   = (int*)p; p += NG * 4;
    int* ge   = (int*)p; p += NG * 4;

    const int* srcv = ei;
    const int* dstv = ei + NE;

    int nb = (NN + 1023) / 1024;  // 49
    hipLaunchKernelGGL(k_zero_ints, dim3((2 * NN + 255) / 256), dim3(256), 0, stream, deg, 2 * NN);
    hipLaunchKernelGGL(k_count_deg, dim3((NE + 255) / 256), dim3(256), 0, stream, dstv, deg);
    hipLaunchKernelGGL(k_scan1, dim3(nb), dim3(256), 0, stream, deg, bsum);
    hipLaunchKernelGGL(k_scan2, dim3(1), dim3(64), 0, stream, bsum, nb, row_ptr);
    hipLaunchKernelGGL(k_scan3, dim3(nb), dim3(256), 0, stream, deg, bsum, row_ptr);
    hipLaunchKernelGGL(k_fill, dim3((NE + 255) / 256), dim3(256), 0, stream, srcv, dstv, row_ptr, fill, col);
    hipLaunchKernelGGL(k_ranges_init, dim3(1), dim3(256), 0, stream, gs, ge);
    hipLaunchKernelGGL(k_ranges, dim3((NN + 255) / 256), dim3(256), 0, stream, batch, gs, ge);

    int aggBlocks  = (NN * 64 + 255) / 256;  // 12500
    int gemmBlocks = (NN + 31) / 32;         // 1563

    // layer 0 (in 128 ch)
    hipLaunchKernelGGL(k_agg0, dim3(aggBlocks), dim3(256), 0, stream, x, row_ptr, col, Tb);
    hipLaunchKernelGGL((k_gemm<128>), dim3(gemmBlocks), dim3(256), 0, stream, Tb, w1_0, b1_0, Hb);
    hipLaunchKernelGGL((k_gemm<256>), dim3(gemmBlocks), dim3(256), 0, stream, Hb, w2_0, b2_0, Hb);  // in-place safe

    // layers 1..3
    for (int l = 0; l < 3; l++) {
        hipLaunchKernelGGL(k_agg, dim3(aggBlocks), dim3(256), 0, stream, Hb, row_ptr, col, Tb);
        hipLaunchKernelGGL((k_gemm<256>), dim3(gemmBlocks), dim3(256), 0, stream,
                           Tb, w1s + (size_t)l * CH * CH, b1s + (size_t)l * CH, Tb);  // in-place safe
        hipLaunchKernelGGL((k_gemm<256>), dim3(gemmBlocks), dim3(256), 0, stream,
                           Tb, w2s + (size_t)l * CH * CH, b2s + (size_t)l * CH, Hb);
    }

    hipLaunchKernelGGL(k_pool, dim3(NG), dim3(256), 0, stream, Hb, gs, ge, out);
}

// Round 5
// 998.720 us; speedup vs baseline: 1.5242x; 1.5242x over previous
//
#include <hip/hip_runtime.h>
#include <hip/hip_bf16.h>

#define NN 50000   // nodes
#define NE 800000  // edges
#define NG 256     // graphs
#define CIN 128
#define CH 256

typedef unsigned short u16;
typedef unsigned int u32;
typedef __attribute__((ext_vector_type(8))) short short8;   // 8 bf16 = 4 VGPRs
typedef __attribute__((ext_vector_type(4))) float f32x4;

__device__ __forceinline__ float bf2f(u16 u) { return __uint_as_float(((u32)u) << 16); }
__device__ __forceinline__ u16 f2bf(float f) {
    u32 u = __float_as_uint(f);
    return (u16)((u + 0x7fffu + ((u >> 16) & 1u)) >> 16);  // RNE
}

// ---------------- CSR build ----------------
__global__ void k_zero_ints(int* p, int n) {
    int i = blockIdx.x * 256 + threadIdx.x;
    if (i < n) p[i] = 0;
}

__global__ void k_count_deg(const int* __restrict__ dst, int* __restrict__ deg) {
    int e = blockIdx.x * 256 + threadIdx.x;
    if (e < NE) atomicAdd(&deg[dst[e]], 1);
}

__global__ void k_scan1(const int* __restrict__ deg, int* __restrict__ bsum) {
    __shared__ int sd[256];
    int base = blockIdx.x * 1024, t = threadIdx.x, s = 0;
    for (int j = 0; j < 4; j++) { int i = base + t * 4 + j; if (i < NN) s += deg[i]; }
    sd[t] = s; __syncthreads();
    for (int off = 128; off > 0; off >>= 1) { if (t < off) sd[t] += sd[t + off]; __syncthreads(); }
    if (t == 0) bsum[blockIdx.x] = sd[0];
}

__global__ void k_scan2(int* bsum, int nb, int* row_ptr) {
    if (threadIdx.x == 0 && blockIdx.x == 0) {
        int acc = 0;
        for (int i = 0; i < nb; i++) { int v = bsum[i]; bsum[i] = acc; acc += v; }
        row_ptr[NN] = NE;
    }
}

__global__ void k_scan3(const int* __restrict__ deg, const int* __restrict__ bsum,
                        int* __restrict__ row_ptr) {
    __shared__ int sd[256];
    int base = blockIdx.x * 1024, t = threadIdx.x;
    int v[4]; int s = 0;
    for (int j = 0; j < 4; j++) { int i = base + t * 4 + j; v[j] = (i < NN) ? deg[i] : 0; s += v[j]; }
    sd[t] = s; __syncthreads();
    for (int off = 1; off < 256; off <<= 1) {
        int tmp = (t >= off) ? sd[t - off] : 0; __syncthreads();
        sd[t] += tmp; __syncthreads();
    }
    int run = bsum[blockIdx.x] + sd[t] - s;
    for (int j = 0; j < 4; j++) { int i = base + t * 4 + j; if (i < NN) row_ptr[i] = run; run += v[j]; }
}

__global__ void k_fill(const int* __restrict__ src, const int* __restrict__ dst,
                       const int* __restrict__ row_ptr, int* __restrict__ fill,
                       int* __restrict__ col) {
    int e = blockIdx.x * 256 + threadIdx.x;
    if (e < NE) {
        int d = dst[e];
        int pos = row_ptr[d] + atomicAdd(&fill[d], 1);
        col[pos] = src[e];
    }
}

// ---------------- input convert fp32 -> bf16 ----------------
__global__ void k_cvt_x(const float* __restrict__ x, u16* __restrict__ xb) {
    int t = blockIdx.x * 256 + threadIdx.x;           // one float4 per thread
    if (t >= NN * CIN / 4) return;
    float4 v = ((const float4*)x)[t];
    ushort4 o; o.x = f2bf(v.x); o.y = f2bf(v.y); o.z = f2bf(v.z); o.w = f2bf(v.w);
    ((ushort4*)xb)[t] = o;
}

// ---------------- weight pack: W[KxN fp32] -> MFMA B-fragment order bf16 ----
// Wp[o], o = ((kb*16 + nt)*64 + lane)*8 + j  holds  W[kb*32 + (lane>>4)*8 + j][nt*16 + (lane&15)]
__global__ void k_pack(const float* __restrict__ W, u16* __restrict__ Wp, int n) {
    int o = blockIdx.x * 256 + threadIdx.x;
    if (o >= n) return;
    int j = o & 7, lane = (o >> 3) & 63, nt = (o >> 9) & 15, kb = o >> 13;
    int k = kb * 32 + ((lane >> 4) << 3) + j;
    int nc = nt * 16 + (lane & 15);
    Wp[o] = f2bf(W[k * CH + nc]);
}

// ---------------- aggregation (bf16 storage, fp32 accumulate) ----------------
__global__ void k_agg0_b(const u16* __restrict__ x, const int* __restrict__ row_ptr,
                         const int* __restrict__ col, u16* __restrict__ z) {
    int gid = blockIdx.x * 256 + threadIdx.x;
    int node = gid >> 6, lane = threadIdx.x & 63;
    if (node >= NN) return;
    int c0 = lane * 2;
    ushort2 sv = *(const ushort2*)(x + (size_t)node * CIN + c0);
    float a0 = bf2f(sv.x), a1 = bf2f(sv.y);
    int beg = row_ptr[node], end = row_ptr[node + 1];
    for (int e = beg; e < end; e++) {
        int s = col[e];
        ushort2 nv = *(const ushort2*)(x + (size_t)s * CIN + c0);
        a0 += bf2f(nv.x); a1 += bf2f(nv.y);
    }
    ushort2 o; o.x = f2bf(a0); o.y = f2bf(a1);
    *(ushort2*)(z + (size_t)node * CIN + c0) = o;
}

__global__ void k_agg_b(const u16* __restrict__ h, const int* __restrict__ row_ptr,
                        const int* __restrict__ col, u16* __restrict__ z) {
    int gid = blockIdx.x * 256 + threadIdx.x;
    int node = gid >> 6, lane = threadIdx.x & 63;
    if (node >= NN) return;
    int c0 = lane * 4;
    ushort4 sv = *(const ushort4*)(h + (size_t)node * CH + c0);
    float a0 = bf2f(sv.x), a1 = bf2f(sv.y), a2 = bf2f(sv.z), a3 = bf2f(sv.w);
    int beg = row_ptr[node], end = row_ptr[node + 1];
    for (int e = beg; e < end; e++) {
        int s = col[e];
        ushort4 nv = *(const ushort4*)(h + (size_t)s * CH + c0);
        a0 += bf2f(nv.x); a1 += bf2f(nv.y); a2 += bf2f(nv.z); a3 += bf2f(nv.w);
    }
    ushort4 o; o.x = f2bf(a0); o.y = f2bf(a1); o.z = f2bf(a2); o.w = f2bf(a3);
    *(ushort4*)(z + (size_t)node * CH + c0) = o;
}

// ---------------- MFMA GEMM + bias + relu ----------------
// out[M x 256] = relu(A[M x K] @ W[K x 256] + b); A,out bf16; Wp packed bf16; bias fp32
// block = 64 rows x 256 cols, 4 waves (wave w owns cols [w*64, w*64+64))
// NOT in-place: caller guarantees out != A.
template <int K>
__global__ __launch_bounds__(256) void k_gemm_mfma(const u16* __restrict__ A,
                                                   const u16* __restrict__ Wp,
                                                   const float* __restrict__ bias,
                                                   u16* __restrict__ out) {
    __shared__ __align__(16) u16 Bs[8192];  // 16 KB: one K-step slice of packed W
    int tid = threadIdx.x;
    int wave = tid >> 6, lane = tid & 63;
    int quad = lane >> 4, l16 = lane & 15;
    int m0 = blockIdx.x * 64;

    f32x4 acc[4][4];
#pragma unroll
    for (int ri = 0; ri < 4; ri++)
#pragma unroll
        for (int nj = 0; nj < 4; nj++) acc[ri][nj] = (f32x4){0.f, 0.f, 0.f, 0.f};

    int arow[4];
#pragma unroll
    for (int ri = 0; ri < 4; ri++) {
        int r = m0 + ri * 16 + l16;
        arow[ri] = (r < NN) ? r : (NN - 1);
    }

    const int KB = K / 32;
    for (int kb = 0; kb < KB; kb++) {
        __syncthreads();  // previous iteration's Bs reads done
        const uint4* g = (const uint4*)(Wp + kb * 8192);
        uint4* s = (uint4*)Bs;
        s[tid] = g[tid]; s[tid + 256] = g[tid + 256];
        s[tid + 512] = g[tid + 512]; s[tid + 768] = g[tid + 768];
        __syncthreads();

        int ka = kb * 32 + quad * 8;
        short8 a[4];
#pragma unroll
        for (int ri = 0; ri < 4; ri++)
            a[ri] = *(const short8*)(A + (size_t)arow[ri] * K + ka);
#pragma unroll
        for (int nj = 0; nj < 4; nj++) {
            int nt = wave * 4 + nj;
            short8 b = *(const short8*)(Bs + (nt * 64 + lane) * 8);
#pragma unroll
            for (int ri = 0; ri < 4; ri++)
                acc[ri][nj] = __builtin_amdgcn_mfma_f32_16x16x32_bf16(a[ri], b, acc[ri][nj], 0, 0, 0);
        }
    }
    __syncthreads();  // all reads done before any stores (defensive)

#pragma unroll
    for (int nj = 0; nj < 4; nj++) {
        int colc = wave * 64 + nj * 16 + l16;
        float bv = bias[colc];
#pragma unroll
        for (int ri = 0; ri < 4; ri++) {
            int rbase = m0 + ri * 16 + quad * 4;
            f32x4 v = acc[ri][nj];
#pragma unroll
            for (int j = 0; j < 4; j++) {
                int row = rbase + j;
                if (row < NN) out[(size_t)row * CH + colc] = f2bf(fmaxf(v[j] + bv, 0.f));
            }
        }
    }
}

// ---------------- global_add_pool ----------------
__global__ void k_ranges_init(int* gs, int* ge) {
    int g = threadIdx.x;
    gs[g] = NN; ge[g] = 0;
}
__global__ void k_ranges(const int* __restrict__ batch, int* gs, int* ge) {
    int i = blockIdx.x * 256 + threadIdx.x;
    if (i < NN) { int b = batch[i]; atomicMin(&gs[b], i); atomicMax(&ge[b], i + 1); }
}
__global__ void k_pool(const u16* __restrict__ h, const int* __restrict__ gs,
                       const int* __restrict__ ge, float* __restrict__ out) {
    int g = blockIdx.x, c = threadIdx.x;
    int s = gs[g], e = ge[g];
    float acc = 0.f;
    for (int i = s; i < e; i++) acc += bf2f(h[(size_t)i * CH + c]);
    out[g * CH + c] = acc;
}

extern "C" void kernel_launch(void* const* d_in, const int* in_sizes, int n_in,
                              void* d_out, int out_size, void* d_ws, size_t ws_size,
                              hipStream_t stream) {
    const float* x     = (const float*)d_in[0];
    const int*   ei    = (const int*)d_in[1];
    const int*   batch = (const int*)d_in[2];
    const float* w1_0  = (const float*)d_in[3];
    const float* b1_0  = (const float*)d_in[4];
    const float* w2_0  = (const float*)d_in[5];
    const float* b2_0  = (const float*)d_in[6];
    const float* w1s   = (const float*)d_in[7];
    const float* b1s   = (const float*)d_in[8];
    const float* w2s   = (const float*)d_in[9];
    const float* b2s   = (const float*)d_in[10];
    float* out = (float*)d_out;

    char* p = (char*)d_ws;
    u16* Hb  = (u16*)p; p += (size_t)NN * CH * 2;    // 25.6 MB
    u16* Tb  = (u16*)p; p += (size_t)NN * CH * 2;    // 25.6 MB
    u16* T0b = (u16*)p; p += (size_t)NN * CIN * 2;   // 12.8 MB
    u16* xb  = (u16*)p; p += (size_t)NN * CIN * 2;   // 12.8 MB
    // FIX (round 4 crash): 7 CH x CH matrices are packed (w2_0 + 3x(w1s,w2s)),
    // previous rounds allocated only 6 -> last k_pack overflowed 128 KB into
    // row_ptr -> wild gather ranges in k_agg0_b -> GPU page fault / abort.
    u16* WpA = (u16*)p; p += (size_t)(CIN * CH + 7 * CH * CH) * 2;
    int* row_ptr = (int*)p; p += (size_t)(NN + 1) * 4;
    int* deg  = (int*)p; p += (size_t)NN * 4;
    int* fill = (int*)p; p += (size_t)NN * 4;   // adjacent to deg (zeroed together)
    int* col  = (int*)p; p += (size_t)NE * 4;
    int* bsum = (int*)p; p += 64 * 4;
    int* gs   = (int*)p; p += NG * 4;
    int* ge   = (int*)p; p += NG * 4;

    // packed weight offsets
    u16* Wp1_0 = WpA;                        // 128x256
    u16* Wp2_0 = Wp1_0 + CIN * CH;           // 256x256
    u16* Wp1s[3], *Wp2s[3];
    {
        u16* q = Wp2_0 + CH * CH;
        for (int l = 0; l < 3; l++) { Wp1s[l] = q; q += CH * CH; Wp2s[l] = q; q += CH * CH; }
    }

    const int* srcv = ei;
    const int* dstv = ei + NE;

    int nb = (NN + 1023) / 1024;  // 49
    hipLaunchKernelGGL(k_zero_ints, dim3((2 * NN + 255) / 256), dim3(256), 0, stream, deg, 2 * NN);
    hipLaunchKernelGGL(k_count_deg, dim3((NE + 255) / 256), dim3(256), 0, stream, dstv, deg);
    hipLaunchKernelGGL(k_scan1, dim3(nb), dim3(256), 0, stream, deg, bsum);
    hipLaunchKernelGGL(k_scan2, dim3(1), dim3(64), 0, stream, bsum, nb, row_ptr);
    hipLaunchKernelGGL(k_scan3, dim3(nb), dim3(256), 0, stream, deg, bsum, row_ptr);
    hipLaunchKernelGGL(k_fill, dim3((NE + 255) / 256), dim3(256), 0, stream, srcv, dstv, row_ptr, fill, col);
    hipLaunchKernelGGL(k_ranges_init, dim3(1), dim3(256), 0, stream, gs, ge);
    hipLaunchKernelGGL(k_ranges, dim3((NN + 255) / 256), dim3(256), 0, stream, batch, gs, ge);

    hipLaunchKernelGGL(k_cvt_x, dim3((NN * CIN / 4 + 255) / 256), dim3(256), 0, stream, x, xb);
    hipLaunchKernelGGL(k_pack, dim3((CIN * CH + 255) / 256), dim3(256), 0, stream, w1_0, Wp1_0, CIN * CH);
    hipLaunchKernelGGL(k_pack, dim3((CH * CH + 255) / 256), dim3(256), 0, stream, w2_0, Wp2_0, CH * CH);
    for (int l = 0; l < 3; l++) {
        hipLaunchKernelGGL(k_pack, dim3((CH * CH + 255) / 256), dim3(256), 0, stream,
                           w1s + (size_t)l * CH * CH, Wp1s[l], CH * CH);
        hipLaunchKernelGGL(k_pack, dim3((CH * CH + 255) / 256), dim3(256), 0, stream,
                           w2s + (size_t)l * CH * CH, Wp2s[l], CH * CH);
    }

    int aggBlocks  = (NN * 64 + 255) / 256;  // 12500
    int gemmBlocks = (NN + 63) / 64;         // 782

    // layer 0: xb -> T0b -> Hb -> Tb   (no in-place anywhere)
    hipLaunchKernelGGL(k_agg0_b, dim3(aggBlocks), dim3(256), 0, stream, xb, row_ptr, col, T0b);
    hipLaunchKernelGGL((k_gemm_mfma<128>), dim3(gemmBlocks), dim3(256), 0, stream, T0b, Wp1_0, b1_0, Hb);
    hipLaunchKernelGGL((k_gemm_mfma<256>), dim3(gemmBlocks), dim3(256), 0, stream, Hb, Wp2_0, b2_0, Tb);

    // layers 1..3: ping-pong, src != dst always
    u16* h = Tb;
    for (int l = 0; l < 3; l++) {
        u16* t1 = (h == Tb) ? Hb : Tb;
        hipLaunchKernelGGL(k_agg_b, dim3(aggBlocks), dim3(256), 0, stream, h, row_ptr, col, t1);
        hipLaunchKernelGGL((k_gemm_mfma<256>), dim3(gemmBlocks), dim3(256), 0, stream,
                           t1, Wp1s[l], b1s + (size_t)l * CH, h);
        hipLaunchKernelGGL((k_gemm_mfma<256>), dim3(gemmBlocks), dim3(256), 0, stream,
                           h, Wp2s[l], b2s + (size_t)l * CH, t1);
        h = t1;
    }
    // after loop h == Hb

    hipLaunchKernelGGL(k_pool, dim3(NG), dim3(256), 0, stream, h, gs, ge, out);
}

// Round 6
// 731.542 us; speedup vs baseline: 2.0809x; 1.3652x over previous
//
#include <hip/hip_runtime.h>
#include <hip/hip_bf16.h>

#define NN 50000   // nodes
#define NE 800000  // edges
#define NG 256     // graphs
#define CIN 128
#define CH 256

typedef unsigned short u16;
typedef unsigned int u32;
typedef __attribute__((ext_vector_type(8))) short short8;   // 8 bf16 = 4 VGPRs
typedef __attribute__((ext_vector_type(4))) float f32x4;

__device__ __forceinline__ float bf2f(u16 u) { return __uint_as_float(((u32)u) << 16); }
__device__ __forceinline__ u16 f2bf(float f) {
    u32 u = __float_as_uint(f);
    return (u16)((u + 0x7fffu + ((u >> 16) & 1u)) >> 16);  // RNE
}

// ---------------- init: zero deg/fill + init pool ranges ----------------
__global__ void k_init(int* __restrict__ deg_fill, int* __restrict__ gs, int* __restrict__ ge) {
    int i = blockIdx.x * 256 + threadIdx.x;
    if (i < 2 * NN) deg_fill[i] = 0;
    if (i < NG) { gs[i] = NN; ge[i] = 0; }
}

// ---------------- CSR build ----------------
__global__ void k_count_deg(const int* __restrict__ dst, int* __restrict__ deg) {
    int e = blockIdx.x * 256 + threadIdx.x;
    if (e < NE) atomicAdd(&deg[dst[e]], 1);
}

__global__ void k_scan1(const int* __restrict__ deg, int* __restrict__ bsum) {
    __shared__ int sd[256];
    int base = blockIdx.x * 1024, t = threadIdx.x, s = 0;
    for (int j = 0; j < 4; j++) { int i = base + t * 4 + j; if (i < NN) s += deg[i]; }
    sd[t] = s; __syncthreads();
    for (int off = 128; off > 0; off >>= 1) { if (t < off) sd[t] += sd[t + off]; __syncthreads(); }
    if (t == 0) bsum[blockIdx.x] = sd[0];
}

__global__ void k_scan2(int* bsum, int nb, int* row_ptr) {
    if (threadIdx.x == 0 && blockIdx.x == 0) {
        int acc = 0;
        for (int i = 0; i < nb; i++) { int v = bsum[i]; bsum[i] = acc; acc += v; }
        row_ptr[NN] = NE;
    }
}

__global__ void k_scan3(const int* __restrict__ deg, const int* __restrict__ bsum,
                        int* __restrict__ row_ptr) {
    __shared__ int sd[256];
    int base = blockIdx.x * 1024, t = threadIdx.x;
    int v[4]; int s = 0;
    for (int j = 0; j < 4; j++) { int i = base + t * 4 + j; v[j] = (i < NN) ? deg[i] : 0; s += v[j]; }
    sd[t] = s; __syncthreads();
    for (int off = 1; off < 256; off <<= 1) {
        int tmp = (t >= off) ? sd[t - off] : 0; __syncthreads();
        sd[t] += tmp; __syncthreads();
    }
    int run = bsum[blockIdx.x] + sd[t] - s;
    for (int j = 0; j < 4; j++) { int i = base + t * 4 + j; if (i < NN) row_ptr[i] = run; run += v[j]; }
}

__global__ void k_fill(const int* __restrict__ src, const int* __restrict__ dst,
                       const int* __restrict__ row_ptr, int* __restrict__ fill,
                       int* __restrict__ col) {
    int e = blockIdx.x * 256 + threadIdx.x;
    if (e < NE) {
        int d = dst[e];
        int pos = row_ptr[d] + atomicAdd(&fill[d], 1);
        col[pos] = src[e];
    }
}

__global__ void k_ranges(const int* __restrict__ batch, int* gs, int* ge) {
    int i = blockIdx.x * 256 + threadIdx.x;
    if (i < NN) { int b = batch[i]; atomicMin(&gs[b], i); atomicMax(&ge[b], i + 1); }
}

// ---------------- input convert fp32 -> bf16 ----------------
__global__ void k_cvt_x(const float* __restrict__ x, u16* __restrict__ xb) {
    int t = blockIdx.x * 256 + threadIdx.x;
    if (t >= NN * CIN / 4) return;
    float4 v = ((const float4*)x)[t];
    ushort4 o; o.x = f2bf(v.x); o.y = f2bf(v.y); o.z = f2bf(v.z); o.w = f2bf(v.w);
    ((ushort4*)xb)[t] = o;
}

// ---------------- weight pack: W[KxN fp32] -> MFMA B-fragment order bf16 ----
// Wp[o], o = ((kb*16 + nt)*64 + lane)*8 + j  holds  W[kb*32 + (lane>>4)*8 + j][nt*16 + (lane&15)]
// PER = elements per matrix (pow2); handles [count] stacked matrices.
template <int PER>
__global__ void k_pack(const float* __restrict__ W, u16* __restrict__ Wp, int n) {
    int o = blockIdx.x * 256 + threadIdx.x;
    if (o >= n) return;
    int l = o / PER, rem = o & (PER - 1);
    int j = rem & 7, lane = (rem >> 3) & 63, nt = (rem >> 9) & 15, kb = rem >> 13;
    int k = kb * 32 + ((lane >> 4) << 3) + j;
    int nc = nt * 16 + (lane & 15);
    Wp[o] = f2bf(W[(size_t)l * PER + k * CH + nc]);
}

// ---------------- aggregation (bf16 storage, fp32 accumulate, unroll-4 MLP) ----
__global__ void k_agg0_b(const u16* __restrict__ x, const int* __restrict__ row_ptr,
                         const int* __restrict__ col, u16* __restrict__ z) {
    int gid = blockIdx.x * 256 + threadIdx.x;
    int node = gid >> 6, lane = threadIdx.x & 63;
    if (node >= NN) return;
    int c0 = lane * 2;
    ushort2 sv = *(const ushort2*)(x + (size_t)node * CIN + c0);
    float a0 = bf2f(sv.x), a1 = bf2f(sv.y);
    int beg = row_ptr[node], end = row_ptr[node + 1];
    int e = beg;
    for (; e + 4 <= end; e += 4) {
        int s0 = col[e], s1 = col[e + 1], s2 = col[e + 2], s3 = col[e + 3];
        ushort2 v0 = *(const ushort2*)(x + (size_t)s0 * CIN + c0);
        ushort2 v1 = *(const ushort2*)(x + (size_t)s1 * CIN + c0);
        ushort2 v2 = *(const ushort2*)(x + (size_t)s2 * CIN + c0);
        ushort2 v3 = *(const ushort2*)(x + (size_t)s3 * CIN + c0);
        a0 += bf2f(v0.x) + bf2f(v1.x) + bf2f(v2.x) + bf2f(v3.x);
        a1 += bf2f(v0.y) + bf2f(v1.y) + bf2f(v2.y) + bf2f(v3.y);
    }
    for (; e < end; e++) {
        int s = col[e];
        ushort2 nv = *(const ushort2*)(x + (size_t)s * CIN + c0);
        a0 += bf2f(nv.x); a1 += bf2f(nv.y);
    }
    ushort2 o; o.x = f2bf(a0); o.y = f2bf(a1);
    *(ushort2*)(z + (size_t)node * CIN + c0) = o;
}

__global__ void k_agg_b(const u16* __restrict__ h, const int* __restrict__ row_ptr,
                        const int* __restrict__ col, u16* __restrict__ z) {
    int gid = blockIdx.x * 256 + threadIdx.x;
    int node = gid >> 6, lane = threadIdx.x & 63;
    if (node >= NN) return;
    int c0 = lane * 4;
    ushort4 sv = *(const ushort4*)(h + (size_t)node * CH + c0);
    float a0 = bf2f(sv.x), a1 = bf2f(sv.y), a2 = bf2f(sv.z), a3 = bf2f(sv.w);
    int beg = row_ptr[node], end = row_ptr[node + 1];
    int e = beg;
    for (; e + 4 <= end; e += 4) {
        int s0 = col[e], s1 = col[e + 1], s2 = col[e + 2], s3 = col[e + 3];
        ushort4 v0 = *(const ushort4*)(h + (size_t)s0 * CH + c0);
        ushort4 v1 = *(const ushort4*)(h + (size_t)s1 * CH + c0);
        ushort4 v2 = *(const ushort4*)(h + (size_t)s2 * CH + c0);
        ushort4 v3 = *(const ushort4*)(h + (size_t)s3 * CH + c0);
        a0 += bf2f(v0.x) + bf2f(v1.x) + bf2f(v2.x) + bf2f(v3.x);
        a1 += bf2f(v0.y) + bf2f(v1.y) + bf2f(v2.y) + bf2f(v3.y);
        a2 += bf2f(v0.z) + bf2f(v1.z) + bf2f(v2.z) + bf2f(v3.z);
        a3 += bf2f(v0.w) + bf2f(v1.w) + bf2f(v2.w) + bf2f(v3.w);
    }
    for (; e < end; e++) {
        int s = col[e];
        ushort4 nv = *(const ushort4*)(h + (size_t)s * CH + c0);
        a0 += bf2f(nv.x); a1 += bf2f(nv.y); a2 += bf2f(nv.z); a3 += bf2f(nv.w);
    }
    ushort4 o; o.x = f2bf(a0); o.y = f2bf(a1); o.z = f2bf(a2); o.w = f2bf(a3);
    *(ushort4*)(z + (size_t)node * CH + c0) = o;
}

// ---------------- fused MLP: out = relu(relu(A@W1+b1)@W2+b2) ----------------
// A [NN x K1] bf16, W packed in B-frag order (no LDS staging: each wave's
// b-fragments are disjoint 16B-coalesced global reads, L2-hot).
// block = 64 rows x 256 cols, 4 waves; z1 round-trips through LDS.
#define Z1S 264  // z1 row stride in u16 (padded: 264*2B=528B -> bank spread)
template <int K1>
__global__ __launch_bounds__(256) void k_mlp(const u16* __restrict__ A,
                                             const u16* __restrict__ Wp1,
                                             const float* __restrict__ b1,
                                             const u16* __restrict__ Wp2,
                                             const float* __restrict__ b2,
                                             u16* __restrict__ out) {
    __shared__ __align__(16) u16 z1[64 * Z1S];  // 33.8 KB
    int tid = threadIdx.x;
    int wave = tid >> 6, lane = tid & 63;
    int quad = lane >> 4, l16 = lane & 15;
    int m0 = blockIdx.x * 64;

    f32x4 acc[4][4];
#pragma unroll
    for (int ri = 0; ri < 4; ri++)
#pragma unroll
        for (int nj = 0; nj < 4; nj++) acc[ri][nj] = (f32x4){0.f, 0.f, 0.f, 0.f};

    int arow[4];
#pragma unroll
    for (int ri = 0; ri < 4; ri++) {
        int r = m0 + ri * 16 + l16;
        arow[ri] = (r < NN) ? r : (NN - 1);
    }

    // ---- GEMM1: a,b straight from global; no barriers ----
#pragma unroll
    for (int kb = 0; kb < K1 / 32; kb++) {
        int ka = kb * 32 + quad * 8;
        short8 a[4];
#pragma unroll
        for (int ri = 0; ri < 4; ri++)
            a[ri] = *(const short8*)(A + (size_t)arow[ri] * K1 + ka);
#pragma unroll
        for (int nj = 0; nj < 4; nj++) {
            short8 b = *(const short8*)(Wp1 + ((size_t)(kb * 16 + wave * 4 + nj) * 64 + lane) * 8);
#pragma unroll
            for (int ri = 0; ri < 4; ri++)
                acc[ri][nj] = __builtin_amdgcn_mfma_f32_16x16x32_bf16(a[ri], b, acc[ri][nj], 0, 0, 0);
        }
    }

    // ---- bias1 + relu -> z1 (LDS, row-major, padded stride) ----
#pragma unroll
    for (int nj = 0; nj < 4; nj++) {
        float bv = b1[wave * 64 + nj * 16 + l16];
        int cc = wave * 64 + nj * 16 + l16;
#pragma unroll
        for (int ri = 0; ri < 4; ri++) {
            f32x4 v = acc[ri][nj];
#pragma unroll
            for (int j = 0; j < 4; j++) {
                int rl = ri * 16 + quad * 4 + j;
                z1[rl * Z1S + cc] = f2bf(fmaxf(v[j] + bv, 0.f));
            }
        }
    }
    __syncthreads();

    // ---- GEMM2: a from LDS, b from global; K = 256 ----
#pragma unroll
    for (int ri = 0; ri < 4; ri++)
#pragma unroll
        for (int nj = 0; nj < 4; nj++) acc[ri][nj] = (f32x4){0.f, 0.f, 0.f, 0.f};

#pragma unroll
    for (int kb = 0; kb < 8; kb++) {
        short8 a[4];
#pragma unroll
        for (int ri = 0; ri < 4; ri++)
            a[ri] = *(const short8*)(z1 + (ri * 16 + l16) * Z1S + kb * 32 + quad * 8);
#pragma unroll
        for (int nj = 0; nj < 4; nj++) {
            short8 b = *(const short8*)(Wp2 + ((size_t)(kb * 16 + wave * 4 + nj) * 64 + lane) * 8);
#pragma unroll
            for (int ri = 0; ri < 4; ri++)
                acc[ri][nj] = __builtin_amdgcn_mfma_f32_16x16x32_bf16(a[ri], b, acc[ri][nj], 0, 0, 0);
        }
    }
    __syncthreads();  // z1 reads done before overwrite

    // ---- bias2 + relu -> z1, then coalesced global store ----
#pragma unroll
    for (int nj = 0; nj < 4; nj++) {
        float bv = b2[wave * 64 + nj * 16 + l16];
        int cc = wave * 64 + nj * 16 + l16;
#pragma unroll
        for (int ri = 0; ri < 4; ri++) {
            f32x4 v = acc[ri][nj];
#pragma unroll
            for (int j = 0; j < 4; j++) {
                int rl = ri * 16 + quad * 4 + j;
                z1[rl * Z1S + cc] = f2bf(fmaxf(v[j] + bv, 0.f));
            }
        }
    }
    __syncthreads();

    int row = tid >> 2, cb = (tid & 3) * 64;
    if (m0 + row < NN) {
        uint2* dst = (uint2*)(out + (size_t)(m0 + row) * CH + cb);
        const u16* srcp = z1 + row * Z1S + cb;
#pragma unroll
        for (int c = 0; c < 8; c++) {
            uint2 v = *(const uint2*)(srcp + c * 8);
            // 8 u16 = 16B: use two 8B chunks to keep alignment simple
            dst[c * 2] = v;
            dst[c * 2 + 1] = *(const uint2*)(srcp + c * 8 + 4);
        }
    }
}

// ---------------- global_add_pool ----------------
__global__ void k_pool(const u16* __restrict__ h, const int* __restrict__ gs,
                       const int* __restrict__ ge, float* __restrict__ out) {
    int g = blockIdx.x, c = threadIdx.x;
    int s = gs[g], e = ge[g];
    float acc = 0.f;
    for (int i = s; i < e; i++) acc += bf2f(h[(size_t)i * CH + c]);
    out[g * CH + c] = acc;
}

extern "C" void kernel_launch(void* const* d_in, const int* in_sizes, int n_in,
                              void* d_out, int out_size, void* d_ws, size_t ws_size,
                              hipStream_t stream) {
    const float* x     = (const float*)d_in[0];
    const int*   ei    = (const int*)d_in[1];
    const int*   batch = (const int*)d_in[2];
    const float* w1_0  = (const float*)d_in[3];
    const float* b1_0  = (const float*)d_in[4];
    const float* w2_0  = (const float*)d_in[5];
    const float* b2_0  = (const float*)d_in[6];
    const float* w1s   = (const float*)d_in[7];
    const float* b1s   = (const float*)d_in[8];
    const float* w2s   = (const float*)d_in[9];
    const float* b2s   = (const float*)d_in[10];
    float* out = (float*)d_out;

    char* p = (char*)d_ws;
    u16* Hb  = (u16*)p; p += (size_t)NN * CH * 2;
    u16* Tb  = (u16*)p; p += (size_t)NN * CH * 2;
    u16* T0b = (u16*)p; p += (size_t)NN * CIN * 2;
    u16* xb  = (u16*)p; p += (size_t)NN * CIN * 2;
    u16* WpA = (u16*)p; p += (size_t)(CIN * CH + 7 * CH * CH) * 2;  // 1 + 7 packed mats
    int* row_ptr = (int*)p; p += (size_t)(NN + 1) * 4;
    int* deg  = (int*)p; p += (size_t)NN * 4;
    int* fill = (int*)p; p += (size_t)NN * 4;   // adjacent to deg (zeroed together)
    int* col  = (int*)p; p += (size_t)NE * 4;
    int* bsum = (int*)p; p += 64 * 4;
    int* gs   = (int*)p; p += NG * 4;
    int* ge   = (int*)p; p += NG * 4;

    // packed weight arena: Wp1_0 | Wp2_0 | Wp1s[0..2] | Wp2s[0..2]
    u16* Wp1_0 = WpA;                          // 128x256
    u16* Wp2_0 = Wp1_0 + CIN * CH;             // 256x256
    u16* Wp1sA = Wp2_0 + CH * CH;              // 3 x 256x256 contiguous
    u16* Wp2sA = Wp1sA + 3 * CH * CH;          // 3 x 256x256 contiguous

    const int* srcv = ei;
    const int* dstv = ei + NE;

    int nb = (NN + 1023) / 1024;  // 49
    hipLaunchKernelGGL(k_init, dim3((2 * NN + 255) / 256), dim3(256), 0, stream, deg, gs, ge);
    hipLaunchKernelGGL(k_count_deg, dim3((NE + 255) / 256), dim3(256), 0, stream, dstv, deg);
    hipLaunchKernelGGL(k_scan1, dim3(nb), dim3(256), 0, stream, deg, bsum);
    hipLaunchKernelGGL(k_scan2, dim3(1), dim3(64), 0, stream, bsum, nb, row_ptr);
    hipLaunchKernelGGL(k_scan3, dim3(nb), dim3(256), 0, stream, deg, bsum, row_ptr);
    hipLaunchKernelGGL(k_fill, dim3((NE + 255) / 256), dim3(256), 0, stream, srcv, dstv, row_ptr, fill, col);
    hipLaunchKernelGGL(k_ranges, dim3((NN + 255) / 256), dim3(256), 0, stream, batch, gs, ge);

    hipLaunchKernelGGL(k_cvt_x, dim3((NN * CIN / 4 + 255) / 256), dim3(256), 0, stream, x, xb);
    hipLaunchKernelGGL((k_pack<CIN * CH>), dim3((CIN * CH + 255) / 256), dim3(256), 0, stream,
                       w1_0, Wp1_0, CIN * CH);
    hipLaunchKernelGGL((k_pack<CH * CH>), dim3((CH * CH + 255) / 256), dim3(256), 0, stream,
                       w2_0, Wp2_0, CH * CH);
    hipLaunchKernelGGL((k_pack<CH * CH>), dim3((3 * CH * CH + 255) / 256), dim3(256), 0, stream,
                       w1s, Wp1sA, 3 * CH * CH);
    hipLaunchKernelGGL((k_pack<CH * CH>), dim3((3 * CH * CH + 255) / 256), dim3(256), 0, stream,
                       w2s, Wp2sA, 3 * CH * CH);

    int aggBlocks = (NN * 64 + 255) / 256;  // 12500
    int mlpBlocks = (NN + 63) / 64;         // 782

    // layer 0: xb -> T0b -> Hb
    hipLaunchKernelGGL(k_agg0_b, dim3(aggBlocks), dim3(256), 0, stream, xb, row_ptr, col, T0b);
    hipLaunchKernelGGL((k_mlp<128>), dim3(mlpBlocks), dim3(256), 0, stream,
                       T0b, Wp1_0, b1_0, Wp2_0, b2_0, Hb);

    // layers 1..3: Hb -> Tb -> Hb  (agg gathers from Hb, mlp writes back to Hb)
    for (int l = 0; l < 3; l++) {
        hipLaunchKernelGGL(k_agg_b, dim3(aggBlocks), dim3(256), 0, stream, Hb, row_ptr, col, Tb);
        hipLaunchKernelGGL((k_mlp<256>), dim3(mlpBlocks), dim3(256), 0, stream,
                           Tb, Wp1sA + (size_t)l * CH * CH, b1s + (size_t)l * CH,
                           Wp2sA + (size_t)l * CH * CH, b2s + (size_t)l * CH, Hb);
    }

    hipLaunchKernelGGL(k_pool, dim3(NG), dim3(256), 0, stream, Hb, gs, ge, out);
}

// Round 7
// 599.076 us; speedup vs baseline: 2.5411x; 1.2211x over previous
//
#include <hip/hip_runtime.h>
#include <hip/hip_bf16.h>

#define NN 50000   // nodes
#define NE 800000  // edges
#define NG 256     // graphs
#define CIN 128
#define CH 256

typedef unsigned short u16;
typedef unsigned int u32;
typedef __attribute__((ext_vector_type(8))) short short8;   // 8 bf16 = 4 VGPRs
typedef __attribute__((ext_vector_type(4))) float f32x4;

__device__ __forceinline__ float bf2f(u16 u) { return __uint_as_float(((u32)u) << 16); }
__device__ __forceinline__ u16 f2bf(float f) {
    u32 u = __float_as_uint(f);
    return (u16)((u + 0x7fffu + ((u >> 16) & 1u)) >> 16);  // RNE
}

// ---------------- init: zero deg/fill + zero pool ranges ----------------
__global__ void k_init(int* __restrict__ deg_fill, int* __restrict__ gs, int* __restrict__ ge) {
    int i = blockIdx.x * 256 + threadIdx.x;
    if (i < 2 * NN) deg_fill[i] = 0;
    if (i < NG) { gs[i] = 0; ge[i] = 0; }   // empty graphs -> empty range
}

// ---------------- CSR build ----------------
__global__ void k_count_deg(const int* __restrict__ dst, int* __restrict__ deg) {
    int e = blockIdx.x * 256 + threadIdx.x;
    if (e < NE) atomicAdd(&deg[dst[e]], 1);
}

__global__ void k_scan1(const int* __restrict__ deg, int* __restrict__ bsum) {
    __shared__ int sd[256];
    int base = blockIdx.x * 1024, t = threadIdx.x, s = 0;
    for (int j = 0; j < 4; j++) { int i = base + t * 4 + j; if (i < NN) s += deg[i]; }
    sd[t] = s; __syncthreads();
    for (int off = 128; off > 0; off >>= 1) { if (t < off) sd[t] += sd[t + off]; __syncthreads(); }
    if (t == 0) bsum[blockIdx.x] = sd[0];
}

// single-wave shuffle scan over nb<=64 block sums
__global__ void k_scan2(int* bsum, int nb, int* row_ptr) {
    int lane = threadIdx.x;
    int v = (lane < nb) ? bsum[lane] : 0;
    int s = v;
    for (int off = 1; off < 64; off <<= 1) {
        int t = __shfl_up(s, off, 64);
        if (lane >= off) s += t;
    }
    if (lane < nb) bsum[lane] = s - v;  // exclusive prefix
    if (lane == 0) row_ptr[NN] = NE;
}

__global__ void k_scan3(const int* __restrict__ deg, const int* __restrict__ bsum,
                        int* __restrict__ row_ptr) {
    __shared__ int sd[256];
    int base = blockIdx.x * 1024, t = threadIdx.x;
    int v[4]; int s = 0;
    for (int j = 0; j < 4; j++) { int i = base + t * 4 + j; v[j] = (i < NN) ? deg[i] : 0; s += v[j]; }
    sd[t] = s; __syncthreads();
    for (int off = 1; off < 256; off <<= 1) {
        int tmp = (t >= off) ? sd[t - off] : 0; __syncthreads();
        sd[t] += tmp; __syncthreads();
    }
    int run = bsum[blockIdx.x] + sd[t] - s;
    for (int j = 0; j < 4; j++) { int i = base + t * 4 + j; if (i < NN) row_ptr[i] = run; run += v[j]; }
}

__global__ void k_fill(const int* __restrict__ src, const int* __restrict__ dst,
                       const int* __restrict__ row_ptr, int* __restrict__ fill,
                       int* __restrict__ col) {
    int e = blockIdx.x * 256 + threadIdx.x;
    if (e < NE) {
        int d = dst[e];
        int pos = row_ptr[d] + atomicAdd(&fill[d], 1);
        col[pos] = src[e];
    }
}

// batch is sorted -> graph ranges are boundaries; no atomics
__global__ void k_bounds(const int* __restrict__ batch, int* __restrict__ gs, int* __restrict__ ge) {
    int i = blockIdx.x * 256 + threadIdx.x;
    if (i >= NN) return;
    int b = batch[i];
    if (i == 0 || batch[i - 1] != b) gs[b] = i;
    if (i == NN - 1 || batch[i + 1] != b) ge[b] = i + 1;
}

// ---------------- input convert fp32 -> bf16 ----------------
__global__ void k_cvt_x(const float* __restrict__ x, u16* __restrict__ xb) {
    int t = blockIdx.x * 256 + threadIdx.x;
    if (t >= NN * CIN / 4) return;
    float4 v = ((const float4*)x)[t];
    ushort4 o; o.x = f2bf(v.x); o.y = f2bf(v.y); o.z = f2bf(v.z); o.w = f2bf(v.w);
    ((ushort4*)xb)[t] = o;
}

// ---------------- weight pack: W[KxN fp32] -> MFMA B-fragment order bf16 ----
// Wp[o], o = ((kb*16 + nt)*64 + lane)*8 + j  holds  W[kb*32 + (lane>>4)*8 + j][nt*16 + (lane&15)]
template <int PER>
__global__ void k_pack(const float* __restrict__ W, u16* __restrict__ Wp, int n) {
    int o = blockIdx.x * 256 + threadIdx.x;
    if (o >= n) return;
    int l = o / PER, rem = o & (PER - 1);
    int j = rem & 7, lane = (rem >> 3) & 63, nt = (rem >> 9) & 15, kb = rem >> 13;
    int k = kb * 32 + ((lane >> 4) << 3) + j;
    int nc = nt * 16 + (lane & 15);
    Wp[o] = f2bf(W[(size_t)l * PER + k * CH + nc]);
}

// ---------------- aggregation (bf16 storage, fp32 accumulate, unroll-8) ------
__global__ void k_agg0_b(const u16* __restrict__ x, const int* __restrict__ row_ptr,
                         const int* __restrict__ col, u16* __restrict__ z) {
    int gid = blockIdx.x * 256 + threadIdx.x;
    int node = gid >> 6, lane = threadIdx.x & 63;
    if (node >= NN) return;
    int c0 = lane * 2;
    ushort2 sv = *(const ushort2*)(x + (size_t)node * CIN + c0);
    float a0 = bf2f(sv.x), a1 = bf2f(sv.y);
    int beg = row_ptr[node], end = row_ptr[node + 1];
    int e = beg;
    for (; e + 8 <= end; e += 8) {
        ushort2 v[8];
#pragma unroll
        for (int q = 0; q < 8; q++) v[q] = *(const ushort2*)(x + (size_t)col[e + q] * CIN + c0);
#pragma unroll
        for (int q = 0; q < 8; q++) { a0 += bf2f(v[q].x); a1 += bf2f(v[q].y); }
    }
    for (; e < end; e++) {
        ushort2 nv = *(const ushort2*)(x + (size_t)col[e] * CIN + c0);
        a0 += bf2f(nv.x); a1 += bf2f(nv.y);
    }
    ushort2 o; o.x = f2bf(a0); o.y = f2bf(a1);
    *(ushort2*)(z + (size_t)node * CIN + c0) = o;
}

__global__ void k_agg_b(const u16* __restrict__ h, const int* __restrict__ row_ptr,
                        const int* __restrict__ col, u16* __restrict__ z) {
    int gid = blockIdx.x * 256 + threadIdx.x;
    int node = gid >> 6, lane = threadIdx.x & 63;
    if (node >= NN) return;
    int c0 = lane * 4;
    ushort4 sv = *(const ushort4*)(h + (size_t)node * CH + c0);
    float a0 = bf2f(sv.x), a1 = bf2f(sv.y), a2 = bf2f(sv.z), a3 = bf2f(sv.w);
    int beg = row_ptr[node], end = row_ptr[node + 1];
    int e = beg;
    for (; e + 8 <= end; e += 8) {
        ushort4 v[8];
#pragma unroll
        for (int q = 0; q < 8; q++) v[q] = *(const ushort4*)(h + (size_t)col[e + q] * CH + c0);
#pragma unroll
        for (int q = 0; q < 8; q++) {
            a0 += bf2f(v[q].x); a1 += bf2f(v[q].y); a2 += bf2f(v[q].z); a3 += bf2f(v[q].w);
        }
    }
    for (; e < end; e++) {
        ushort4 nv = *(const ushort4*)(h + (size_t)col[e] * CH + c0);
        a0 += bf2f(nv.x); a1 += bf2f(nv.y); a2 += bf2f(nv.z); a3 += bf2f(nv.w);
    }
    ushort4 o; o.x = f2bf(a0); o.y = f2bf(a1); o.z = f2bf(a2); o.w = f2bf(a3);
    *(ushort4*)(z + (size_t)node * CH + c0) = o;
}

// ---------------- fused MLP: out = relu(relu(A@W1+b1)@W2+b2) ----------------
// block = 64 rows x 256 cols, 4 waves; z1 via LDS; explicit 1-deep register
// software pipeline: prefetch kb+1 fragments before kb's MFMAs.
#define Z1S 264
template <int K1>
__global__ __launch_bounds__(256) void k_mlp(const u16* __restrict__ A,
                                             const u16* __restrict__ Wp1,
                                             const float* __restrict__ b1,
                                             const u16* __restrict__ Wp2,
                                             const float* __restrict__ b2,
                                             u16* __restrict__ out) {
    __shared__ __align__(16) u16 z1[64 * Z1S];  // 33.8 KB
    int tid = threadIdx.x;
    int wave = tid >> 6, lane = tid & 63;
    int quad = lane >> 4, l16 = lane & 15;
    int m0 = blockIdx.x * 64;

    f32x4 acc[4][4];
#pragma unroll
    for (int ri = 0; ri < 4; ri++)
#pragma unroll
        for (int nj = 0; nj < 4; nj++) acc[ri][nj] = (f32x4){0.f, 0.f, 0.f, 0.f};

    int arow[4];
#pragma unroll
    for (int ri = 0; ri < 4; ri++) {
        int r = m0 + ri * 16 + l16;
        arow[ri] = (r < NN) ? r : (NN - 1);
    }

    // b-frag base for this wave: Wp + kb*8192 + (wave*4+nj)*512 + lane*8
    const u16* w1b = Wp1 + (wave * 4) * 512 + lane * 8;
    const u16* w2b = Wp2 + (wave * 4) * 512 + lane * 8;

    // ---- GEMM1 (K1), software-pipelined ----
    const int KB1 = K1 / 32;
    short8 a_cur[4], b_cur[4];
#pragma unroll
    for (int ri = 0; ri < 4; ri++)
        a_cur[ri] = *(const short8*)(A + (size_t)arow[ri] * K1 + quad * 8);
#pragma unroll
    for (int nj = 0; nj < 4; nj++)
        b_cur[nj] = *(const short8*)(w1b + nj * 512);

#pragma unroll
    for (int kb = 0; kb < KB1; kb++) {
        int kn = (kb + 1 < KB1) ? (kb + 1) : kb;   // last prefetch is a dummy re-load
        short8 a_nxt[4], b_nxt[4];
        int ka = kn * 32 + quad * 8;
#pragma unroll
        for (int ri = 0; ri < 4; ri++)
            a_nxt[ri] = *(const short8*)(A + (size_t)arow[ri] * K1 + ka);
#pragma unroll
        for (int nj = 0; nj < 4; nj++)
            b_nxt[nj] = *(const short8*)(w1b + kn * 8192 + nj * 512);
#pragma unroll
        for (int nj = 0; nj < 4; nj++)
#pragma unroll
            for (int ri = 0; ri < 4; ri++)
                acc[ri][nj] = __builtin_amdgcn_mfma_f32_16x16x32_bf16(a_cur[ri], b_cur[nj], acc[ri][nj], 0, 0, 0);
#pragma unroll
        for (int ri = 0; ri < 4; ri++) a_cur[ri] = a_nxt[ri];
#pragma unroll
        for (int nj = 0; nj < 4; nj++) b_cur[nj] = b_nxt[nj];
    }

    // ---- bias1 + relu -> z1 ----
#pragma unroll
    for (int nj = 0; nj < 4; nj++) {
        int cc = wave * 64 + nj * 16 + l16;
        float bv = b1[cc];
#pragma unroll
        for (int ri = 0; ri < 4; ri++) {
            f32x4 v = acc[ri][nj];
#pragma unroll
            for (int j = 0; j < 4; j++)
                z1[(ri * 16 + quad * 4 + j) * Z1S + cc] = f2bf(fmaxf(v[j] + bv, 0.f));
        }
    }
    __syncthreads();

    // ---- GEMM2 (K=256): a from LDS, b prefetched from global ----
#pragma unroll
    for (int ri = 0; ri < 4; ri++)
#pragma unroll
        for (int nj = 0; nj < 4; nj++) acc[ri][nj] = (f32x4){0.f, 0.f, 0.f, 0.f};

#pragma unroll
    for (int nj = 0; nj < 4; nj++) b_cur[nj] = *(const short8*)(w2b + nj * 512);

#pragma unroll
    for (int kb = 0; kb < 8; kb++) {
        int kn = (kb + 1 < 8) ? (kb + 1) : kb;
        short8 b_nxt[4];
#pragma unroll
        for (int nj = 0; nj < 4; nj++)
            b_nxt[nj] = *(const short8*)(w2b + kn * 8192 + nj * 512);
        short8 a[4];
#pragma unroll
        for (int ri = 0; ri < 4; ri++)
            a[ri] = *(const short8*)(z1 + (ri * 16 + l16) * Z1S + kb * 32 + quad * 8);
#pragma unroll
        for (int nj = 0; nj < 4; nj++)
#pragma unroll
            for (int ri = 0; ri < 4; ri++)
                acc[ri][nj] = __builtin_amdgcn_mfma_f32_16x16x32_bf16(a[ri], b_cur[nj], acc[ri][nj], 0, 0, 0);
#pragma unroll
        for (int nj = 0; nj < 4; nj++) b_cur[nj] = b_nxt[nj];
    }
    __syncthreads();  // z1 reads done before overwrite

    // ---- bias2 + relu -> z1, then coalesced store ----
#pragma unroll
    for (int nj = 0; nj < 4; nj++) {
        int cc = wave * 64 + nj * 16 + l16;
        float bv = b2[cc];
#pragma unroll
        for (int ri = 0; ri < 4; ri++) {
            f32x4 v = acc[ri][nj];
#pragma unroll
            for (int j = 0; j < 4; j++)
                z1[(ri * 16 + quad * 4 + j) * Z1S + cc] = f2bf(fmaxf(v[j] + bv, 0.f));
        }
    }
    __syncthreads();

    int row = tid >> 2, cb = (tid & 3) * 64;
    if (m0 + row < NN) {
        uint2* dst = (uint2*)(out + (size_t)(m0 + row) * CH + cb);
        const u16* srcp = z1 + row * Z1S + cb;
#pragma unroll
        for (int c = 0; c < 8; c++) {
            dst[c * 2] = *(const uint2*)(srcp + c * 8);
            dst[c * 2 + 1] = *(const uint2*)(srcp + c * 8 + 4);
        }
    }
}

// ---------------- global_add_pool ----------------
__global__ void k_pool(const u16* __restrict__ h, const int* __restrict__ gs,
                       const int* __restrict__ ge, float* __restrict__ out) {
    int g = blockIdx.x, c = threadIdx.x;
    int s = gs[g], e = ge[g];
    float acc = 0.f;
    for (int i = s; i < e; i++) acc += bf2f(h[(size_t)i * CH + c]);
    out[g * CH + c] = acc;
}

extern "C" void kernel_launch(void* const* d_in, const int* in_sizes, int n_in,
                              void* d_out, int out_size, void* d_ws, size_t ws_size,
                              hipStream_t stream) {
    const float* x     = (const float*)d_in[0];
    const int*   ei    = (const int*)d_in[1];
    const int*   batch = (const int*)d_in[2];
    const float* w1_0  = (const float*)d_in[3];
    const float* b1_0  = (const float*)d_in[4];
    const float* w2_0  = (const float*)d_in[5];
    const float* b2_0  = (const float*)d_in[6];
    const float* w1s   = (const float*)d_in[7];
    const float* b1s   = (const float*)d_in[8];
    const float* w2s   = (const float*)d_in[9];
    const float* b2s   = (const float*)d_in[10];
    float* out = (float*)d_out;

    char* p = (char*)d_ws;
    u16* Hb  = (u16*)p; p += (size_t)NN * CH * 2;
    u16* Tb  = (u16*)p; p += (size_t)NN * CH * 2;
    u16* T0b = (u16*)p; p += (size_t)NN * CIN * 2;
    u16* xb  = (u16*)p; p += (size_t)NN * CIN * 2;
    u16* WpA = (u16*)p; p += (size_t)(CIN * CH + 7 * CH * CH) * 2;  // 1+7 packed mats
    int* row_ptr = (int*)p; p += (size_t)(NN + 1) * 4;
    int* deg  = (int*)p; p += (size_t)NN * 4;
    int* fill = (int*)p; p += (size_t)NN * 4;   // adjacent to deg (zeroed together)
    int* col  = (int*)p; p += (size_t)NE * 4;
    int* bsum = (int*)p; p += 64 * 4;
    int* gs   = (int*)p; p += NG * 4;
    int* ge   = (int*)p; p += NG * 4;

    u16* Wp1_0 = WpA;                          // 128x256
    u16* Wp2_0 = Wp1_0 + CIN * CH;             // 256x256
    u16* Wp1sA = Wp2_0 + CH * CH;              // 3 x 256x256
    u16* Wp2sA = Wp1sA + 3 * CH * CH;          // 3 x 256x256

    const int* srcv = ei;
    const int* dstv = ei + NE;

    int nb = (NN + 1023) / 1024;  // 49
    hipLaunchKernelGGL(k_init, dim3((2 * NN + 255) / 256), dim3(256), 0, stream, deg, gs, ge);
    hipLaunchKernelGGL(k_count_deg, dim3((NE + 255) / 256), dim3(256), 0, stream, dstv, deg);
    hipLaunchKernelGGL(k_scan1, dim3(nb), dim3(256), 0, stream, deg, bsum);
    hipLaunchKernelGGL(k_scan2, dim3(1), dim3(64), 0, stream, bsum, nb, row_ptr);
    hipLaunchKernelGGL(k_scan3, dim3(nb), dim3(256), 0, stream, deg, bsum, row_ptr);
    hipLaunchKernelGGL(k_fill, dim3((NE + 255) / 256), dim3(256), 0, stream, srcv, dstv, row_ptr, fill, col);
    hipLaunchKernelGGL(k_bounds, dim3((NN + 255) / 256), dim3(256), 0, stream, batch, gs, ge);

    hipLaunchKernelGGL(k_cvt_x, dim3((NN * CIN / 4 + 255) / 256), dim3(256), 0, stream, x, xb);
    hipLaunchKernelGGL((k_pack<CIN * CH>), dim3((CIN * CH + 255) / 256), dim3(256), 0, stream,
                       w1_0, Wp1_0, CIN * CH);
    hipLaunchKernelGGL((k_pack<CH * CH>), dim3((CH * CH + 255) / 256), dim3(256), 0, stream,
                       w2_0, Wp2_0, CH * CH);
    hipLaunchKernelGGL((k_pack<CH * CH>), dim3((3 * CH * CH + 255) / 256), dim3(256), 0, stream,
                       w1s, Wp1sA, 3 * CH * CH);
    hipLaunchKernelGGL((k_pack<CH * CH>), dim3((3 * CH * CH + 255) / 256), dim3(256), 0, stream,
                       w2s, Wp2sA, 3 * CH * CH);

    int aggBlocks = (NN * 64 + 255) / 256;  // 12500
    int mlpBlocks = (NN + 63) / 64;         // 782

    // layer 0: xb -> T0b -> Hb
    hipLaunchKernelGGL(k_agg0_b, dim3(aggBlocks), dim3(256), 0, stream, xb, row_ptr, col, T0b);
    hipLaunchKernelGGL((k_mlp<128>), dim3(mlpBlocks), dim3(256), 0, stream,
                       T0b, Wp1_0, b1_0, Wp2_0, b2_0, Hb);

    // layers 1..3: Hb -> Tb -> Hb
    for (int l = 0; l < 3; l++) {
        hipLaunchKernelGGL(k_agg_b, dim3(aggBlocks), dim3(256), 0, stream, Hb, row_ptr, col, Tb);
        hipLaunchKernelGGL((k_mlp<256>), dim3(mlpBlocks), dim3(256), 0, stream,
                           Tb, Wp1sA + (size_t)l * CH * CH, b1s + (size_t)l * CH,
                           Wp2sA + (size_t)l * CH * CH, b2s + (size_t)l * CH, Hb);
    }

    hipLaunchKernelGGL(k_pool, dim3(NG), dim3(256), 0, stream, Hb, gs, ge, out);
}

// Round 8
// 594.027 us; speedup vs baseline: 2.5627x; 1.0085x over previous
//
#include <hip/hip_runtime.h>
#include <hip/hip_bf16.h>

#define NN 50000   // nodes
#define NE 800000  // edges
#define NG 256     // graphs
#define CIN 128
#define CH 256

typedef unsigned short u16;
typedef unsigned int u32;
typedef __attribute__((ext_vector_type(8))) short short8;          // 8 bf16 = 4 VGPRs
typedef __attribute__((ext_vector_type(8))) unsigned short ushort8;
typedef __attribute__((ext_vector_type(4))) float f32x4;

__device__ __forceinline__ float bf2f(u16 u) { return __uint_as_float(((u32)u) << 16); }
__device__ __forceinline__ u16 f2bf(float f) {
    u32 u = __float_as_uint(f);
    return (u16)((u + 0x7fffu + ((u >> 16) & 1u)) >> 16);  // RNE
}

// ---------------- init: zero deg/fill + zero pool ranges ----------------
__global__ void k_init(int* __restrict__ deg_fill, int* __restrict__ gs, int* __restrict__ ge) {
    int i = blockIdx.x * 256 + threadIdx.x;
    if (i < 2 * NN) deg_fill[i] = 0;
    if (i < NG) { gs[i] = 0; ge[i] = 0; }
}

// ---------------- CSR build ----------------
__global__ void k_count_deg(const int* __restrict__ dst, int* __restrict__ deg) {
    int e = blockIdx.x * 256 + threadIdx.x;
    if (e < NE) atomicAdd(&deg[dst[e]], 1);
}

__global__ void k_scan1(const int* __restrict__ deg, int* __restrict__ bsum) {
    __shared__ int sd[256];
    int base = blockIdx.x * 1024, t = threadIdx.x, s = 0;
    for (int j = 0; j < 4; j++) { int i = base + t * 4 + j; if (i < NN) s += deg[i]; }
    sd[t] = s; __syncthreads();
    for (int off = 128; off > 0; off >>= 1) { if (t < off) sd[t] += sd[t + off]; __syncthreads(); }
    if (t == 0) bsum[blockIdx.x] = sd[0];
}

// single-wave shuffle scan over nb<=64 block sums
__global__ void k_scan2(int* bsum, int nb, int* row_ptr) {
    int lane = threadIdx.x;
    int v = (lane < nb) ? bsum[lane] : 0;
    int s = v;
    for (int off = 1; off < 64; off <<= 1) {
        int t = __shfl_up(s, off, 64);
        if (lane >= off) s += t;
    }
    if (lane < nb) bsum[lane] = s - v;  // exclusive prefix
    if (lane == 0) row_ptr[NN] = NE;
}

__global__ void k_scan3(const int* __restrict__ deg, const int* __restrict__ bsum,
                        int* __restrict__ row_ptr) {
    __shared__ int sd[256];
    int base = blockIdx.x * 1024, t = threadIdx.x;
    int v[4]; int s = 0;
    for (int j = 0; j < 4; j++) { int i = base + t * 4 + j; v[j] = (i < NN) ? deg[i] : 0; s += v[j]; }
    sd[t] = s; __syncthreads();
    for (int off = 1; off < 256; off <<= 1) {
        int tmp = (t >= off) ? sd[t - off] : 0; __syncthreads();
        sd[t] += tmp; __syncthreads();
    }
    int run = bsum[blockIdx.x] + sd[t] - s;
    for (int j = 0; j < 4; j++) { int i = base + t * 4 + j; if (i < NN) row_ptr[i] = run; run += v[j]; }
}

__global__ void k_fill(const int* __restrict__ src, const int* __restrict__ dst,
                       const int* __restrict__ row_ptr, int* __restrict__ fill,
                       int* __restrict__ col) {
    int e = blockIdx.x * 256 + threadIdx.x;
    if (e < NE) {
        int d = dst[e];
        int pos = row_ptr[d] + atomicAdd(&fill[d], 1);
        col[pos] = src[e];
    }
}

// batch is sorted -> graph ranges via boundary detection; no atomics
__global__ void k_bounds(const int* __restrict__ batch, int* __restrict__ gs, int* __restrict__ ge) {
    int i = blockIdx.x * 256 + threadIdx.x;
    if (i >= NN) return;
    int b = batch[i];
    if (i == 0 || batch[i - 1] != b) gs[b] = i;
    if (i == NN - 1 || batch[i + 1] != b) ge[b] = i + 1;
}

// ---------------- input convert fp32 -> bf16 ----------------
__global__ void k_cvt_x(const float* __restrict__ x, u16* __restrict__ xb) {
    int t = blockIdx.x * 256 + threadIdx.x;
    if (t >= NN * CIN / 4) return;
    float4 v = ((const float4*)x)[t];
    ushort4 o; o.x = f2bf(v.x); o.y = f2bf(v.y); o.z = f2bf(v.z); o.w = f2bf(v.w);
    ((ushort4*)xb)[t] = o;
}

// ---------------- weight pack: W[KxN fp32] -> MFMA B-fragment order bf16 ----
template <int PER>
__global__ void k_pack(const float* __restrict__ W, u16* __restrict__ Wp, int n) {
    int o = blockIdx.x * 256 + threadIdx.x;
    if (o >= n) return;
    int l = o / PER, rem = o & (PER - 1);
    int j = rem & 7, lane = (rem >> 3) & 63, nt = (rem >> 9) & 15, kb = rem >> 13;
    int k = kb * 32 + ((lane >> 4) << 3) + j;
    int nc = nt * 16 + (lane & 15);
    Wp[o] = f2bf(W[(size_t)l * PER + k * CH + nc]);
}

// ---------------- aggregation: 16B/lane, multiple nodes per wave ------------
// CIN=128: row = 256B = 16 lanes x 16B -> 4 nodes per wave
__global__ void k_agg0_b(const u16* __restrict__ x, const int* __restrict__ row_ptr,
                         const int* __restrict__ col, u16* __restrict__ z) {
    int gid = blockIdx.x * 256 + threadIdx.x;
    int w = gid >> 6, lane = threadIdx.x & 63;
    int node = w * 4 + (lane >> 4);
    if (node >= NN) return;
    int c0 = (lane & 15) * 8;
    const u16* base = x + c0;
    ushort8 sv = *(const ushort8*)(base + (size_t)node * CIN);
    float a[8];
#pragma unroll
    for (int i = 0; i < 8; i++) a[i] = bf2f(sv[i]);
    int beg = row_ptr[node], end = row_ptr[node + 1];
    int e = beg;
    for (; e + 8 <= end; e += 8) {
        ushort8 v[8];
#pragma unroll
        for (int q = 0; q < 8; q++) v[q] = *(const ushort8*)(base + (size_t)col[e + q] * CIN);
#pragma unroll
        for (int q = 0; q < 8; q++)
#pragma unroll
            for (int i = 0; i < 8; i++) a[i] += bf2f(v[q][i]);
    }
    for (; e < end; e++) {
        ushort8 nv = *(const ushort8*)(base + (size_t)col[e] * CIN);
#pragma unroll
        for (int i = 0; i < 8; i++) a[i] += bf2f(nv[i]);
    }
    ushort8 o;
#pragma unroll
    for (int i = 0; i < 8; i++) o[i] = f2bf(a[i]);
    *(ushort8*)(z + (size_t)node * CIN + c0) = o;
}

// CH=256: row = 512B = 32 lanes x 16B -> 2 nodes per wave
__global__ void k_agg_b(const u16* __restrict__ h, const int* __restrict__ row_ptr,
                        const int* __restrict__ col, u16* __restrict__ z) {
    int gid = blockIdx.x * 256 + threadIdx.x;
    int w = gid >> 6, lane = threadIdx.x & 63;
    int node = w * 2 + (lane >> 5);
    if (node >= NN) return;
    int c0 = (lane & 31) * 8;
    const u16* base = h + c0;
    ushort8 sv = *(const ushort8*)(base + (size_t)node * CH);
    float a[8];
#pragma unroll
    for (int i = 0; i < 8; i++) a[i] = bf2f(sv[i]);
    int beg = row_ptr[node], end = row_ptr[node + 1];
    int e = beg;
    for (; e + 8 <= end; e += 8) {
        ushort8 v[8];
#pragma unroll
        for (int q = 0; q < 8; q++) v[q] = *(const ushort8*)(base + (size_t)col[e + q] * CH);
#pragma unroll
        for (int q = 0; q < 8; q++)
#pragma unroll
            for (int i = 0; i < 8; i++) a[i] += bf2f(v[q][i]);
    }
    for (; e < end; e++) {
        ushort8 nv = *(const ushort8*)(base + (size_t)col[e] * CH);
#pragma unroll
        for (int i = 0; i < 8; i++) a[i] += bf2f(nv[i]);
    }
    ushort8 o;
#pragma unroll
    for (int i = 0; i < 8; i++) o[i] = f2bf(a[i]);
    *(ushort8*)(z + (size_t)node * CH + c0) = o;
}

// ---------------- fused MLP: out = relu(relu(A@W1+b1)@W2+b2) ----------------
// 32-row x 256-col block, 4 waves (wave w owns cols [w*64,w*64+64)); z1 via LDS;
// 1-deep register software pipeline on global fragment loads.
#define Z1S 264
template <int K1>
__global__ __launch_bounds__(256) void k_mlp(const u16* __restrict__ A,
                                             const u16* __restrict__ Wp1,
                                             const float* __restrict__ b1,
                                             const u16* __restrict__ Wp2,
                                             const float* __restrict__ b2,
                                             u16* __restrict__ out) {
    __shared__ __align__(16) u16 z1[32 * Z1S];  // 16.9 KB
    int tid = threadIdx.x;
    int wave = tid >> 6, lane = tid & 63;
    int quad = lane >> 4, l16 = lane & 15;
    int m0 = blockIdx.x * 32;

    f32x4 acc[2][4];
#pragma unroll
    for (int ri = 0; ri < 2; ri++)
#pragma unroll
        for (int nj = 0; nj < 4; nj++) acc[ri][nj] = (f32x4){0.f, 0.f, 0.f, 0.f};

    int arow[2];
#pragma unroll
    for (int ri = 0; ri < 2; ri++) {
        int r = m0 + ri * 16 + l16;
        arow[ri] = (r < NN) ? r : (NN - 1);
    }

    const u16* w1b = Wp1 + (wave * 4) * 512 + lane * 8;
    const u16* w2b = Wp2 + (wave * 4) * 512 + lane * 8;

    // ---- GEMM1 (K=K1), software-pipelined ----
    const int KB1 = K1 / 32;
    short8 a_cur[2], b_cur[4];
#pragma unroll
    for (int ri = 0; ri < 2; ri++)
        a_cur[ri] = *(const short8*)(A + (size_t)arow[ri] * K1 + quad * 8);
#pragma unroll
    for (int nj = 0; nj < 4; nj++)
        b_cur[nj] = *(const short8*)(w1b + nj * 512);

#pragma unroll
    for (int kb = 0; kb < KB1; kb++) {
        int kn = (kb + 1 < KB1) ? (kb + 1) : kb;
        short8 a_nxt[2], b_nxt[4];
        int ka = kn * 32 + quad * 8;
#pragma unroll
        for (int ri = 0; ri < 2; ri++)
            a_nxt[ri] = *(const short8*)(A + (size_t)arow[ri] * K1 + ka);
#pragma unroll
        for (int nj = 0; nj < 4; nj++)
            b_nxt[nj] = *(const short8*)(w1b + kn * 8192 + nj * 512);
#pragma unroll
        for (int nj = 0; nj < 4; nj++)
#pragma unroll
            for (int ri = 0; ri < 2; ri++)
                acc[ri][nj] = __builtin_amdgcn_mfma_f32_16x16x32_bf16(a_cur[ri], b_cur[nj], acc[ri][nj], 0, 0, 0);
#pragma unroll
        for (int ri = 0; ri < 2; ri++) a_cur[ri] = a_nxt[ri];
#pragma unroll
        for (int nj = 0; nj < 4; nj++) b_cur[nj] = b_nxt[nj];
    }

    // ---- bias1 + relu -> z1 ----
#pragma unroll
    for (int nj = 0; nj < 4; nj++) {
        int cc = wave * 64 + nj * 16 + l16;
        float bv = b1[cc];
#pragma unroll
        for (int ri = 0; ri < 2; ri++) {
            f32x4 v = acc[ri][nj];
#pragma unroll
            for (int j = 0; j < 4; j++)
                z1[(ri * 16 + quad * 4 + j) * Z1S + cc] = f2bf(fmaxf(v[j] + bv, 0.f));
        }
    }
    __syncthreads();

    // ---- GEMM2 (K=256): a from LDS, b prefetched from global ----
#pragma unroll
    for (int ri = 0; ri < 2; ri++)
#pragma unroll
        for (int nj = 0; nj < 4; nj++) acc[ri][nj] = (f32x4){0.f, 0.f, 0.f, 0.f};

#pragma unroll
    for (int nj = 0; nj < 4; nj++) b_cur[nj] = *(const short8*)(w2b + nj * 512);

#pragma unroll
    for (int kb = 0; kb < 8; kb++) {
        int kn = (kb + 1 < 8) ? (kb + 1) : kb;
        short8 b_nxt[4];
#pragma unroll
        for (int nj = 0; nj < 4; nj++)
            b_nxt[nj] = *(const short8*)(w2b + kn * 8192 + nj * 512);
        short8 a[2];
#pragma unroll
        for (int ri = 0; ri < 2; ri++)
            a[ri] = *(const short8*)(z1 + (ri * 16 + l16) * Z1S + kb * 32 + quad * 8);
#pragma unroll
        for (int nj = 0; nj < 4; nj++)
#pragma unroll
            for (int ri = 0; ri < 2; ri++)
                acc[ri][nj] = __builtin_amdgcn_mfma_f32_16x16x32_bf16(a[ri], b_cur[nj], acc[ri][nj], 0, 0, 0);
#pragma unroll
        for (int nj = 0; nj < 4; nj++) b_cur[nj] = b_nxt[nj];
    }
    __syncthreads();  // z1 reads done before overwrite

    // ---- bias2 + relu -> z1, then coalesced 16B stores ----
#pragma unroll
    for (int nj = 0; nj < 4; nj++) {
        int cc = wave * 64 + nj * 16 + l16;
        float bv = b2[cc];
#pragma unroll
        for (int ri = 0; ri < 2; ri++) {
            f32x4 v = acc[ri][nj];
#pragma unroll
            for (int j = 0; j < 4; j++)
                z1[(ri * 16 + quad * 4 + j) * Z1S + cc] = f2bf(fmaxf(v[j] + bv, 0.f));
        }
    }
    __syncthreads();

    int row = tid >> 3, cb = (tid & 7) * 32;
    if (m0 + row < NN) {
        uint4* dst = (uint4*)(out + (size_t)(m0 + row) * CH + cb);
        const u16* srcp = z1 + row * Z1S + cb;
#pragma unroll
        for (int c = 0; c < 4; c++) dst[c] = *(const uint4*)(srcp + c * 8);
    }
}

// ---------------- global_add_pool ----------------
__global__ void k_pool(const u16* __restrict__ h, const int* __restrict__ gs,
                       const int* __restrict__ ge, float* __restrict__ out) {
    int g = blockIdx.x, c = threadIdx.x;
    int s = gs[g], e = ge[g];
    float acc = 0.f;
    for (int i = s; i < e; i++) acc += bf2f(h[(size_t)i * CH + c]);
    out[g * CH + c] = acc;
}

extern "C" void kernel_launch(void* const* d_in, const int* in_sizes, int n_in,
                              void* d_out, int out_size, void* d_ws, size_t ws_size,
                              hipStream_t stream) {
    const float* x     = (const float*)d_in[0];
    const int*   ei    = (const int*)d_in[1];
    const int*   batch = (const int*)d_in[2];
    const float* w1_0  = (const float*)d_in[3];
    const float* b1_0  = (const float*)d_in[4];
    const float* w2_0  = (const float*)d_in[5];
    const float* b2_0  = (const float*)d_in[6];
    const float* w1s   = (const float*)d_in[7];
    const float* b1s   = (const float*)d_in[8];
    const float* w2s   = (const float*)d_in[9];
    const float* b2s   = (const float*)d_in[10];
    float* out = (float*)d_out;

    char* p = (char*)d_ws;
    u16* Hb  = (u16*)p; p += (size_t)NN * CH * 2;
    u16* Tb  = (u16*)p; p += (size_t)NN * CH * 2;
    u16* T0b = (u16*)p; p += (size_t)NN * CIN * 2;
    u16* xb  = (u16*)p; p += (size_t)NN * CIN * 2;
    u16* WpA = (u16*)p; p += (size_t)(CIN * CH + 7 * CH * CH) * 2;  // 1+7 packed mats
    int* row_ptr = (int*)p; p += (size_t)(NN + 1) * 4;
    int* deg  = (int*)p; p += (size_t)NN * 4;
    int* fill = (int*)p; p += (size_t)NN * 4;   // adjacent to deg (zeroed together)
    int* col  = (int*)p; p += (size_t)NE * 4;
    int* bsum = (int*)p; p += 64 * 4;
    int* gs   = (int*)p; p += NG * 4;
    int* ge   = (int*)p; p += NG * 4;

    u16* Wp1_0 = WpA;                          // 128x256
    u16* Wp2_0 = Wp1_0 + CIN * CH;             // 256x256
    u16* Wp1sA = Wp2_0 + CH * CH;              // 3 x 256x256
    u16* Wp2sA = Wp1sA + 3 * CH * CH;          // 3 x 256x256

    const int* srcv = ei;
    const int* dstv = ei + NE;

    int nb = (NN + 1023) / 1024;  // 49
    hipLaunchKernelGGL(k_init, dim3((2 * NN + 255) / 256), dim3(256), 0, stream, deg, gs, ge);
    hipLaunchKernelGGL(k_count_deg, dim3((NE + 255) / 256), dim3(256), 0, stream, dstv, deg);
    hipLaunchKernelGGL(k_scan1, dim3(nb), dim3(256), 0, stream, deg, bsum);
    hipLaunchKernelGGL(k_scan2, dim3(1), dim3(64), 0, stream, bsum, nb, row_ptr);
    hipLaunchKernelGGL(k_scan3, dim3(nb), dim3(256), 0, stream, deg, bsum, row_ptr);
    hipLaunchKernelGGL(k_fill, dim3((NE + 255) / 256), dim3(256), 0, stream, srcv, dstv, row_ptr, fill, col);
    hipLaunchKernelGGL(k_bounds, dim3((NN + 255) / 256), dim3(256), 0, stream, batch, gs, ge);

    hipLaunchKernelGGL(k_cvt_x, dim3((NN * CIN / 4 + 255) / 256), dim3(256), 0, stream, x, xb);
    hipLaunchKernelGGL((k_pack<CIN * CH>), dim3((CIN * CH + 255) / 256), dim3(256), 0, stream,
                       w1_0, Wp1_0, CIN * CH);
    hipLaunchKernelGGL((k_pack<CH * CH>), dim3((CH * CH + 255) / 256), dim3(256), 0, stream,
                       w2_0, Wp2_0, CH * CH);
    hipLaunchKernelGGL((k_pack<CH * CH>), dim3((3 * CH * CH + 255) / 256), dim3(256), 0, stream,
                       w1s, Wp1sA, 3 * CH * CH);
    hipLaunchKernelGGL((k_pack<CH * CH>), dim3((3 * CH * CH + 255) / 256), dim3(256), 0, stream,
                       w2s, Wp2sA, 3 * CH * CH);

    int agg0Blocks = (NN + 15) / 16;   // 4 nodes/wave, 4 waves/block -> 3125
    int aggBlocks  = (NN + 7) / 8;     // 2 nodes/wave, 4 waves/block -> 6250
    int mlpBlocks  = (NN + 31) / 32;   // 1563

    // layer 0: xb -> T0b -> Hb
    hipLaunchKernelGGL(k_agg0_b, dim3(agg0Blocks), dim3(256), 0, stream, xb, row_ptr, col, T0b);
    hipLaunchKernelGGL((k_mlp<128>), dim3(mlpBlocks), dim3(256), 0, stream,
                       T0b, Wp1_0, b1_0, Wp2_0, b2_0, Hb);

    // layers 1..3: Hb -> Tb -> Hb
    for (int l = 0; l < 3; l++) {
        hipLaunchKernelGGL(k_agg_b, dim3(aggBlocks), dim3(256), 0, stream, Hb, row_ptr, col, Tb);
        hipLaunchKernelGGL((k_mlp<256>), dim3(mlpBlocks), dim3(256), 0, stream,
                           Tb, Wp1sA + (size_t)l * CH * CH, b1s + (size_t)l * CH,
                           Wp2sA + (size_t)l * CH * CH, b2s + (size_t)l * CH, Hb);
    }

    hipLaunchKernelGGL(k_pool, dim3(NG), dim3(256), 0, stream, Hb, gs, ge, out);
}